// Round 6
// baseline (534.625 us; speedup 1.0000x reference)
//
#include <hip/hip_runtime.h>
#include <hip/hip_fp16.h>

// Neural-ODE via fixed-step RK4 (h <= 0.04), f(y) = tanh(y@W1+b1)@W2 + b2.
// One wave integrates 16 points with mfma_f32_16x16x32_f16:
//   H^T = tanh(W1^T @ Y^T + b1), F^T = W2^T @ H^T + b2   (cols = points)
// Fragment maps (16x16x32 f16, all R3-HW-verified):
//   A: lane l holds A[row = l&15][k = (l>>4)*8 + j]
//   B: lane l holds B[k = (l>>4)*8 + j][col = l&15]
//   C/D: lane l holds D[row = (l>>4)*4 + q][col = l&15]
// Weights = VGPR-resident fp16 A-frags. State layout = D-layout:
//   lane (g = l>>4, c = l&15): y[4*mt+q] = Y[pt = c][d = 16*mt + 4*g + q]
// Inter-layer transpose (D-layout -> B-frag) fully in-register:
//   per (kt, qp): 1 permlane32_swap + 2 ds_swizzle(xor16) + 2 cndmask -> 2 dwords.
// No LDS storage at all; 1344 waves (1.31/SIMD) for latency hiding.

#define NB 64
#define NPT 325
#define ND 64
#define NH 128
#define NTOUT 24
#define GP16 21                   // ceil(325/16)
#define NTASK (NB * GP16)         // 1344 single-wave blocks

using f16x8 = __attribute__((ext_vector_type(8))) _Float16;
using f16x2 = __attribute__((ext_vector_type(2))) _Float16;
using f32x4 = __attribute__((ext_vector_type(4))) float;

union Frag { unsigned d[4]; f16x8 v; };

__device__ __forceinline__ unsigned pack2(float lo, float hi) {
  auto pk = __builtin_amdgcn_cvt_pkrtz(lo, hi);
  return __builtin_bit_cast(unsigned, pk);
}

__device__ __forceinline__ float2 unpk(unsigned u) {
  f16x2 h = __builtin_bit_cast(f16x2, u);
  return make_float2((float)h[0], (float)h[1]);
}

// tanh(x) = 1 - 2/(exp2(x*2*log2e) + 1);  x -> -inf: exp2 -> 0 -> -1 exactly.
__device__ __forceinline__ float fast_tanh(float x) {
  float t = fminf(x * 2.885390081777927f, 30.0f);
  float e = __builtin_exp2f(t);          // v_exp_f32 (native exp2)
  float r = __builtin_amdgcn_rcpf(e + 1.0f);
  return fmaf(-2.0f, r, 1.0f);
}

// Route two packed source dwords (a = pk[2kt][qp], b = pk[2kt+1][qp]) into the
// two B-frag dwords (routes rho=0 and rho=1). Derivation in journal; verified
// on concrete lanes. godd = (lane>>4)&1.
__device__ __forceinline__ void route2(unsigned a, unsigned b, bool godd,
                                       unsigned &d_r0, unsigned &d_r1) {
  auto r = __builtin_amdgcn_permlane32_swap((int)a, (int)b, false, false);
  unsigned r0 = (unsigned)r[0], r1 = (unsigned)r[1];
  unsigned s0 = (unsigned)__builtin_amdgcn_ds_swizzle((int)r0, 0x401F);  // lane^16
  unsigned s1 = (unsigned)__builtin_amdgcn_ds_swizzle((int)r1, 0x401F);
  d_r0 = godd ? s1 : r0;
  d_r1 = godd ? r1 : s0;
}

template <bool USE_WS>
__global__ __launch_bounds__(64, 2) void node16_kernel(
    const float* __restrict__ y0g, const float* __restrict__ tsg,
    const float* __restrict__ W1g, const float* __restrict__ b1g,
    const float* __restrict__ W2g, const float* __restrict__ b2g,
    float* __restrict__ outg, float* __restrict__ wsg) {
  const int lane = threadIdx.x & 63;
  const int c = lane & 15;
  const int g = lane >> 4;
  const bool godd = (g & 1) != 0;

  const int task = blockIdx.x;
  const int b = task / GP16;
  const int p0 = (task - b * GP16) * 16;

  // ---- weights as fp16 A-fragments (W^T), VGPR-resident ----
  f16x8 wf1[8][2];  // W1^T[hid=16rt+c][d = 32kt+8g+j] = W1g[d*NH + hid]
#pragma unroll
  for (int rt = 0; rt < 8; ++rt)
#pragma unroll
    for (int kt = 0; kt < 2; ++kt) {
      f16x8 a;
#pragma unroll
      for (int j = 0; j < 8; ++j)
        a[j] = (_Float16)W1g[(32 * kt + 8 * g + j) * NH + 16 * rt + c];
      wf1[rt][kt] = a;
    }
  f16x8 wf2[4][4];  // W2^T[d=16rt+c][hid = 32kt+8g+j] = W2g[hid*ND + d]
#pragma unroll
  for (int rt = 0; rt < 4; ++rt)
#pragma unroll
    for (int kt = 0; kt < 4; ++kt) {
      f16x8 a;
#pragma unroll
      for (int j = 0; j < 8; ++j)
        a[j] = (_Float16)W2g[(32 * kt + 8 * g + j) * ND + 16 * rt + c];
      wf2[rt][kt] = a;
    }

  // ---- biases packed f16 in D-layout rows (hid/d = 16rt + 4g + q) ----
  unsigned b1p[16];
#pragma unroll
  for (int rt = 0; rt < 8; ++rt)
#pragma unroll
    for (int qp = 0; qp < 2; ++qp)
      b1p[2 * rt + qp] =
          pack2(b1g[16 * rt + 4 * g + 2 * qp], b1g[16 * rt + 4 * g + 2 * qp + 1]);
  unsigned b2p[8];
#pragma unroll
  for (int rt = 0; rt < 4; ++rt)
#pragma unroll
    for (int qp = 0; qp < 2; ++qp)
      b2p[2 * rt + qp] =
          pack2(b2g[16 * rt + 4 * g + 2 * qp], b2g[16 * rt + 4 * g + 2 * qp + 1]);

  // ---- state ----
  const int ptc = p0 + c;
  const bool valid = ptc < NPT;
  const int qpt = b * NPT + min(ptc, NPT - 1);

  float y[16], y5[16];
#pragma unroll
  for (int mt = 0; mt < 4; ++mt) {
    float4 v = *(const float4*)&y0g[qpt * ND + 16 * mt + 4 * g];
    y[4 * mt + 0] = v.x; y[4 * mt + 1] = v.y;
    y[4 * mt + 2] = v.z; y[4 * mt + 3] = v.w;
  }

  // build the two B-frags (K=64) of a state-like vector given by val(i)
  auto mk = [&](auto&& val, f16x8 yb[2]) {
#pragma unroll
    for (int kt = 0; kt < 2; ++kt) {
      Frag F;
#pragma unroll
      for (int qp = 0; qp < 2; ++qp) {
        unsigned a = pack2(val(8 * kt + 2 * qp), val(8 * kt + 2 * qp + 1));
        unsigned bb = pack2(val(8 * kt + 4 + 2 * qp), val(8 * kt + 4 + 2 * qp + 1));
        route2(a, bb, godd, F.d[qp], F.d[2 + qp]);
      }
      yb[kt] = F.v;
    }
  };

  f32x4 acc2[4];
  auto feval = [&](const f16x8 yb[2]) {
    f16x8 hb[4];
#pragma unroll
    for (int hf = 0; hf < 2; ++hf) {  // layer-1 in two halves to cap VGPR
      f32x4 acc[4];
#pragma unroll
      for (int rtl = 0; rtl < 4; ++rtl) {
        int rt = 4 * hf + rtl;
        float2 u01 = unpk(b1p[2 * rt]), u23 = unpk(b1p[2 * rt + 1]);
        f32x4 a0 = {u01.x, u01.y, u23.x, u23.y};
        a0 = __builtin_amdgcn_mfma_f32_16x16x32_f16(wf1[rt][0], yb[0], a0, 0, 0, 0);
        a0 = __builtin_amdgcn_mfma_f32_16x16x32_f16(wf1[rt][1], yb[1], a0, 0, 0, 0);
        acc[rtl] = a0;
      }
      float hv[16];
#pragma unroll
      for (int rtl = 0; rtl < 4; ++rtl)
#pragma unroll
        for (int q = 0; q < 4; ++q) hv[4 * rtl + q] = fast_tanh(acc[rtl][q]);
#pragma unroll
      for (int ktl = 0; ktl < 2; ++ktl) {
        Frag F;
#pragma unroll
        for (int qp = 0; qp < 2; ++qp) {
          unsigned a = pack2(hv[8 * ktl + 2 * qp], hv[8 * ktl + 2 * qp + 1]);
          unsigned bb = pack2(hv[8 * ktl + 4 + 2 * qp], hv[8 * ktl + 4 + 2 * qp + 1]);
          route2(a, bb, godd, F.d[qp], F.d[2 + qp]);
        }
        hb[2 * hf + ktl] = F.v;
      }
    }
#pragma unroll
    for (int rt = 0; rt < 4; ++rt) {
      float2 u01 = unpk(b2p[2 * rt]), u23 = unpk(b2p[2 * rt + 1]);
      acc2[rt] = f32x4{u01.x, u01.y, u23.x, u23.y};
    }
#pragma unroll
    for (int kt = 0; kt < 4; ++kt)
#pragma unroll
      for (int rt = 0; rt < 4; ++rt)
        acc2[rt] = __builtin_amdgcn_mfma_f32_16x16x32_f16(wf2[rt][kt], hb[kt], acc2[rt], 0, 0, 0);
  };

#define FV(i) (acc2[(i) >> 2][(i) & 3])

  auto store_k = [&](int k) {
    if (!valid) return;
#pragma unroll
    for (int mt = 0; mt < 4; ++mt) {
      float4 v = make_float4(y[4 * mt], y[4 * mt + 1], y[4 * mt + 2], y[4 * mt + 3]);
      if (USE_WS) {
        *(float4*)&wsg[(size_t)qpt * (ND * NTOUT) + k * ND + 16 * mt + 4 * g] = v;
      } else {
        const size_t base = (size_t)qpt * (ND * NTOUT);
        const int d0 = 16 * mt + 4 * g;
        outg[base + (d0 + 0) * NTOUT + k] = v.x;
        outg[base + (d0 + 1) * NTOUT + k] = v.y;
        outg[base + (d0 + 2) * NTOUT + k] = v.z;
        outg[base + (d0 + 3) * NTOUT + k] = v.w;
      }
    }
  };

  float tprev = tsg[b];
  store_k(0);

  f16x8 yb[2];
  for (int k = 1; k < NTOUT; ++k) {
    float tnext = tsg[k * NB + b];
    float dt = tnext - tprev;
    int n = (int)ceilf(dt * 25.0f);  // h <= 0.04
    n = n < 1 ? 1 : n;
    float h = dt / (float)n;
    float h2 = 0.5f * h;
    float h6 = h * (1.0f / 6.0f);
    float h3 = 2.0f * h6;

    for (int s = 0; s < n; ++s) {
      mk([&](int i) { return y[i]; }, yb);
      feval(yb);  // k1
#pragma unroll
      for (int i = 0; i < 16; ++i) y5[i] = fmaf(h6, FV(i), y[i]);
      mk([&](int i) { return fmaf(h2, FV(i), y[i]); }, yb);
      feval(yb);  // k2
#pragma unroll
      for (int i = 0; i < 16; ++i) y5[i] = fmaf(h3, FV(i), y5[i]);
      mk([&](int i) { return fmaf(h2, FV(i), y[i]); }, yb);
      feval(yb);  // k3
#pragma unroll
      for (int i = 0; i < 16; ++i) y5[i] = fmaf(h3, FV(i), y5[i]);
      mk([&](int i) { return fmaf(h, FV(i), y[i]); }, yb);
      feval(yb);  // k4
#pragma unroll
      for (int i = 0; i < 16; ++i) y[i] = fmaf(h6, FV(i), y5[i]);
    }
    store_k(k);
    tprev = tnext;
  }
#undef FV
}

// ws[q][k][d] -> out[q][d][k]
__global__ __launch_bounds__(256) void transpose_kernel(
    const float* __restrict__ ws, float* __restrict__ out) {
  __shared__ float lds[4 * 24 * 65];
  const int qb = blockIdx.x * 4;
  for (int i = threadIdx.x; i < 4 * 1536; i += 256) {
    int p = i / 1536, idx = i - p * 1536;  // idx = k*64 + d
    int k = idx >> 6, d = idx & 63;
    lds[p * 1560 + k * 65 + d] = ws[(size_t)(qb + p) * 1536 + idx];
  }
  __syncthreads();
  for (int i = threadIdx.x; i < 4 * 1536; i += 256) {
    int p = i / 1536, jdx = i - p * 1536;  // jdx = d*24 + k
    int d = jdx / 24, k = jdx - d * 24;
    out[(size_t)(qb + p) * 1536 + jdx] = lds[p * 1560 + k * 65 + d];
  }
}

extern "C" void kernel_launch(void* const* d_in, const int* in_sizes, int n_in,
                              void* d_out, int out_size, void* d_ws, size_t ws_size,
                              hipStream_t stream) {
  const float* y0 = (const float*)d_in[0];
  const float* ts = (const float*)d_in[1];
  const float* W1 = (const float*)d_in[2];
  const float* b1 = (const float*)d_in[3];
  const float* W2 = (const float*)d_in[4];
  const float* b2 = (const float*)d_in[5];
  float* out = (float*)d_out;
  float* ws = (float*)d_ws;

  const size_t need = (size_t)NB * NPT * ND * NTOUT * sizeof(float);  // 127.8 MB
  if (ws_size >= need) {
    hipLaunchKernelGGL((node16_kernel<true>), dim3(NTASK), dim3(64), 0,
                       stream, y0, ts, W1, b1, W2, b2, out, ws);
    hipLaunchKernelGGL(transpose_kernel, dim3(NB * NPT / 4), dim3(256), 0,
                       stream, ws, out);
  } else {
    hipLaunchKernelGGL((node16_kernel<false>), dim3(NTASK), dim3(64), 0,
                       stream, y0, ts, W1, b1, W2, b2, out, ws);
  }
}